// Round 2
// baseline (153.610 us; speedup 1.0000x reference)
//
#include <hip/hip_runtime.h>

// Corr1d_x: out[n,ch,h,w] = (1/C) * sum_c img1[n,c,h,w] * img2[n,c,h,w + (ch-23)]
// Shapes: img1,img2 [8,256,128,256] fp32; out [8,27,128,256] fp32.
// v2: WT=4 (one wave per row, ds_read_b128 windows), C split x2 across waves,
//     one-time LDS reduction. 512 blocks x 256 thr, 2 blocks/CU.

#define N_      8
#define C_      256
#define H_      128
#define W_      256
#define NCH     27
#define CHUNK   8            // c-slices per barrier (per wave)
#define CHALF   128          // C per wave
#define NCHUNK  (CHALF / CHUNK)   // 16
#define LROW    288          // 24 left pad + 256 + 8 right pad
#define PADL    24
#define STAGE_FLOATS (2 * 4 * CHUNK * LROW)   // dbuf x 4 wave-groups = 73728 B

__device__ __forceinline__ void async_cp16(const float* g, float* l) {
  __builtin_amdgcn_global_load_lds(
      (const __attribute__((address_space(1))) void*)g,
      (__attribute__((address_space(3))) void*)l,
      16, 0, 0);
}

__global__ __launch_bounds__(256, 2)
void corr1d_kernel(const float* __restrict__ img1,
                   const float* __restrict__ img2,
                   float* __restrict__ out) {
  __shared__ __align__(16) float smem[STAGE_FLOATS];

  const int tid    = threadIdx.x;
  const int wv     = tid >> 6;        // 0..3
  const int lane   = tid & 63;
  const int rowsel = wv >> 1;         // which row of the block's pair
  const int chalf  = wv & 1;          // which C half
  const int w0     = lane << 2;       // lane owns outputs w0..w0+3

  const int gh = (blockIdx.x << 1) + rowsel;   // global (n,h) row id
  const int n  = gh >> 7;
  const int h  = gh & (H_ - 1);

  // Zero staging LDS once; pads [0,24) and [280,288) stay zero forever
  // (implements the shift zero-padding).
  {
    float4 z = make_float4(0.f, 0.f, 0.f, 0.f);
    float4* s4 = (float4*)smem;
    #pragma unroll
    for (int i = 0; i < STAGE_FLOATS / 4 / 256; ++i)
      s4[tid + i * 256] = z;
  }
  __syncthreads();

  const size_t plane = (size_t)H_ * W_;
  const float* i1p = img1 + ((size_t)n * C_ + chalf * CHALF) * plane
                          + (size_t)h * W_ + w0;
  const float* i2p = img2 + ((size_t)n * C_ + chalf * CHALF) * plane
                          + (size_t)h * W_ + w0;   // lane*16B for gload_lds

  float4 p[CHUNK];          // img1 values for current chunk
  float4 acc[NCH];
  #pragma unroll
  for (int ch = 0; ch < NCH; ++ch) acc[ch] = make_float4(0.f, 0.f, 0.f, 0.f);

  auto stage = [&](int c0, int buf) {
    // this wave stages its own 8 img2 rows, 1 instr per 1KB row
    #pragma unroll
    for (int r = 0; r < CHUNK; ++r)
      async_cp16(i2p + (size_t)(c0 + r) * plane,
                 &smem[(size_t)(((buf << 2) + wv) * CHUNK + r) * LROW + PADL]);
  };

  stage(0, 0);
  #pragma unroll
  for (int r = 0; r < CHUNK; ++r)
    p[r] = *(const float4*)(i1p + (size_t)r * plane);

  for (int k = 0; k < NCHUNK; ++k) {
    const int buf = k & 1;
    __syncthreads();                  // chunk k staged (vmcnt drained) for all waves
    const bool more = (k + 1 < NCHUNK);
    if (more) stage((k + 1) * CHUNK, buf ^ 1);
    const int c0n = (k + 1) * CHUNK;

    #pragma unroll
    for (int r = 0; r < CHUNK; ++r) {
      const float4 a = p[r];
      if (more)                        // issue next-chunk img1 load early
        p[r] = *(const float4*)(i1p + (size_t)(c0n + r) * plane);
      // padded slot w+24 holds img2[w]; base slot index (w0-24)+24 = w0
      const float4* lrow =
          (const float4*)&smem[(size_t)(((buf << 2) + wv) * CHUNK + r) * LROW + w0];
      float f[32];
      #pragma unroll
      for (int q = 0; q < 8; ++q) {    // 8x ds_read_b128, stride-16B across lanes
        float4 t = lrow[q];
        f[4 * q] = t.x; f[4 * q + 1] = t.y; f[4 * q + 2] = t.z; f[4 * q + 3] = t.w;
      }
      #pragma unroll
      for (int ch = 0; ch < NCH; ++ch) {
        // img2[w0+j+ch-23] -> f[j+ch+1]
        acc[ch].x = fmaf(a.x, f[ch + 1], acc[ch].x);
        acc[ch].y = fmaf(a.y, f[ch + 2], acc[ch].y);
        acc[ch].z = fmaf(a.z, f[ch + 3], acc[ch].z);
        acc[ch].w = fmaf(a.w, f[ch + 4], acc[ch].w);
      }
    }
  }

  // Combine the two C-halves: chalf 1 writes to LDS, chalf 0 adds + stores.
  __syncthreads();                     // done reading staging; safe to overwrite
  if (chalf == 1) {
    float4* dst = (float4*)&smem[(size_t)((rowsel << 6) + lane) * (NCH * 4)];
    #pragma unroll
    for (int ch = 0; ch < NCH; ++ch) dst[ch] = acc[ch];
  }
  __syncthreads();
  if (chalf == 0) {
    const float4* src =
        (const float4*)&smem[(size_t)((rowsel << 6) + lane) * (NCH * 4)];
    const float scale = 1.0f / C_;
    float* op = out + (size_t)n * NCH * plane + (size_t)h * W_ + w0;
    #pragma unroll
    for (int ch = 0; ch < NCH; ++ch) {
      float4 s = src[ch];
      float4 v = make_float4((acc[ch].x + s.x) * scale,
                             (acc[ch].y + s.y) * scale,
                             (acc[ch].z + s.z) * scale,
                             (acc[ch].w + s.w) * scale);
      *(float4*)(op + (size_t)ch * plane) = v;
    }
  }
}

extern "C" void kernel_launch(void* const* d_in, const int* in_sizes, int n_in,
                              void* d_out, int out_size, void* d_ws, size_t ws_size,
                              hipStream_t stream) {
  const float* img1 = (const float*)d_in[0];
  const float* img2 = (const float*)d_in[1];
  float* out = (float*)d_out;
  corr1d_kernel<<<dim3((N_ * H_) / 2), dim3(256), 0, stream>>>(img1, img2, out);
}